// Round 8
// baseline (1374.894 us; speedup 1.0000x reference)
//
#include <hip/hip_runtime.h>
#include <hip/hip_bf16.h>

#define T_LEN 256
#define B_SZ  256
#define EMB   128
#define UNITS 100
#define GATES 400           // 4*UNITS
#define NCOL  800           // c-space: [fwd 400 | bwd 400], c = dir*400 + gate*100 + unit
#define UPAD  104           // padded unit dim in xwF
#define HROW  136           // h-plane row stride (f16 elems)
#define NTILE 4             // 32 tiles / 8 waves (tiles >= 25 inactive)

typedef __attribute__((ext_vector_type(8))) short short8v;
typedef __attribute__((ext_vector_type(4))) short short4v;
typedef __attribute__((ext_vector_type(4))) float f32x4;
typedef __attribute__((ext_vector_type(8))) _Float16 half8;
typedef __attribute__((ext_vector_type(4))) _Float16 half4;

// xwF geometry: element (dir, t, tile=b>>4, unit, lr=b&15) -> uint2 (4 bf16 gates)
#define DIRSZ8 ((size_t)T_LEN * 16 * UPAD * 16)       // uint2 per dir
#define DIRSH  (DIRSZ8 * 4)                            // shorts per dir

static __device__ __forceinline__ float bf2f(short s) {
    unsigned u = ((unsigned)(unsigned short)s) << 16;
    return __builtin_bit_cast(float, u);
}
static __device__ __forceinline__ short f2bf(float f) {
    return __builtin_bit_cast(short, __float2bfloat16(f));
}
static __device__ __forceinline__ float fast_sigmoid(float x) {
    return 1.f / (1.f + __expf(-x));
}
static __device__ __forceinline__ float fast_tanh(float x) {
    return 1.f - 2.f / (1.f + __expf(2.f * x));
}

// ---------------------------------------------------------------------------
// prep: (a) WbT bf16 transposed word-part weights  (b) P_pos/P_dep tables
//       (c) MFMA lane-layout probes: flag[0]=bf16, flag[1]=f16
// ---------------------------------------------------------------------------
#define PREP_WT_BLOCKS 100
#define PREP_TAB_BLOCKS 107

__global__ __launch_bounds__(256) void prep(
    const float* __restrict__ Wf, const float* __restrict__ Wb,
    const float* __restrict__ bf_, const float* __restrict__ bb_,
    const float* __restrict__ Ep, const float* __restrict__ Ed,
    __hip_bfloat16* __restrict__ WbT, float* __restrict__ Ppos,
    float* __restrict__ Pdep, int* __restrict__ flag)
{
    __shared__ short Ap[16 * 32];
    __shared__ short Bp[32 * 16];

    const int bx = blockIdx.x, tid = threadIdx.x;

    if (bx < PREP_WT_BLOCKS) {
        const int base = bx * 1024 + tid * 4;
#pragma unroll
        for (int q = 0; q < 4; ++q) {
            const int id = base + q;            // id = c*128 + k
            const int c = id >> 7, k = id & 127;
            const int dir = c >= GATES;
            const int j = c - dir * GATES;
            const float* W = dir ? Wb : Wf;
            WbT[id] = __float2bfloat16(W[k * GATES + j]);
        }
    } else if (bx < PREP_WT_BLOCKS + PREP_TAB_BLOCKS) {
        const int p = bx - PREP_WT_BLOCKS;
        const bool isPos = p < 53;
        const float* Erow = isPos ? (Ep + p * EMB) : (Ed + (size_t)(p - 53) * EMB);
        const int rowoff = isPos ? EMB : 2 * EMB;
        float* dst = isPos ? (Ppos + (size_t)p * NCOL) : (Pdep + (size_t)(p - 53) * NCOL);
        for (int c = tid; c < NCOL; c += 256) {
            const int dir = c >= GATES;
            const int j = c - dir * GATES;
            const float* W = dir ? Wb : Wf;
            float s = 0.f;
            for (int k = 0; k < EMB; ++k)
                s = fmaf(Erow[k], W[(size_t)(rowoff + k) * GATES + j], s);
            if (!isPos) s += (dir ? bb_[j] : bf_[j]);
            dst[c] = s;
        }
    } else {
        // ---- bf16 probe ----
        if (tid < 64) {
            for (int e = tid; e < 512; e += 64) {
                const int m = e >> 5, k = e & 31;
                Ap[e] = f2bf((float)((m * 3 + k * 5) % 7 - 3));
            }
            for (int e = tid; e < 512; e += 64) {
                const int k = e >> 4, n = e & 15;
                Bp[e] = f2bf((float)((k * 7 + n * 3) % 5 - 2));
            }
        }
        __syncthreads();
        if (tid < 64) {
            const int l = tid, mn = l & 15, grp = l >> 4;
            float ref[4];
#pragma unroll
            for (int i = 0; i < 4; ++i) {
                const int m = grp * 4 + i;
                float s = 0.f;
                for (int k = 0; k < 32; ++k)
                    s += bf2f(Ap[m * 32 + k]) * bf2f(Bp[k * 16 + mn]);
                ref[i] = s;
            }
            short8v a8, b8;
#pragma unroll
            for (int e = 0; e < 8; ++e) {
                const int k8 = grp * 8 + e;
                a8[e] = Ap[mn * 32 + k8];
                b8[e] = Bp[k8 * 16 + mn];
            }
            f32x4 z = {0.f, 0.f, 0.f, 0.f};
            f32x4 d8 = __builtin_amdgcn_mfma_f32_16x16x32_bf16(a8, b8, z, 0, 0, 0);
            const bool ok8 = (d8[0] == ref[0]) && (d8[1] == ref[1]) &&
                             (d8[2] == ref[2]) && (d8[3] == ref[3]);
            const unsigned long long m8 = __ballot(ok8);
            if (tid == 0) flag[0] = (m8 == ~0ULL) ? 0 : 1;
        }
        __syncthreads();
        // ---- f16 probe ----
        if (tid < 64) {
            for (int e = tid; e < 512; e += 64) {
                const int m = e >> 5, k = e & 31;
                Ap[e] = __builtin_bit_cast(short, (_Float16)(float)((m * 3 + k * 5) % 7 - 3));
            }
            for (int e = tid; e < 512; e += 64) {
                const int k = e >> 4, n = e & 15;
                Bp[e] = __builtin_bit_cast(short, (_Float16)(float)((k * 7 + n * 3) % 5 - 2));
            }
        }
        __syncthreads();
        if (tid < 64) {
            const int l = tid, mn = l & 15, grp = l >> 4;
            float ref[4];
#pragma unroll
            for (int i = 0; i < 4; ++i) {
                const int m = grp * 4 + i;
                float s = 0.f;
                for (int k = 0; k < 32; ++k)
                    s += (float)__builtin_bit_cast(_Float16, Ap[m * 32 + k]) *
                         (float)__builtin_bit_cast(_Float16, Bp[k * 16 + mn]);
                ref[i] = s;
            }
            half8 a8, b8;
#pragma unroll
            for (int e = 0; e < 8; ++e) {
                const int k8 = grp * 8 + e;
                a8[e] = __builtin_bit_cast(_Float16, Ap[mn * 32 + k8]);
                b8[e] = __builtin_bit_cast(_Float16, Bp[k8 * 16 + mn]);
            }
            f32x4 z = {0.f, 0.f, 0.f, 0.f};
            f32x4 d8 = __builtin_amdgcn_mfma_f32_16x16x32_f16(a8, b8, z, 0, 0, 0);
            const bool ok8 = (d8[0] == ref[0]) && (d8[1] == ref[1]) &&
                             (d8[2] == ref[2]) && (d8[3] == ref[3]);
            const unsigned long long m8 = __ballot(ok8);
            if (tid == 0) flag[1] = (m8 == ~0ULL) ? 0 : 1;
        }
    }
}

// ---------------------------------------------------------------------------
// embed_gemm: writes fragment-ordered xwF directly.
// ---------------------------------------------------------------------------
#define MT 64
#define NT 160

__global__ __launch_bounds__(256) void embed_gemm(
    const int* __restrict__ words, const int* __restrict__ pos, const int* __restrict__ dep,
    const float* __restrict__ Ew, const __hip_bfloat16* __restrict__ WbT,
    const float* __restrict__ Ppos, const float* __restrict__ Pdep,
    const int* __restrict__ flag, __hip_bfloat16* __restrict__ xwF)
{
    __shared__ __align__(16) short As[MT * 128];
    __shared__ __align__(16) short Bs[NT * 128];
    __shared__ int widx[MT], pidx[MT], didx[MT];

    const int tid = threadIdx.x;
    const int bx = blockIdx.x, by = blockIdx.y;
    const int r0 = bx * MT;
    const int t = r0 >> 8, b0 = r0 & 255;
    const int n0 = by * NT;

    if (tid < MT)             widx[tid]          = words[(size_t)(b0 + tid) * T_LEN + t];
    else if (tid < 2 * MT)    pidx[tid - MT]     = pos[(size_t)(b0 + tid - MT) * T_LEN + t];
    else if (tid < 3 * MT)    didx[tid - 2 * MT] = dep[(size_t)(b0 + tid - 2 * MT) * T_LEN + t];
    __syncthreads();

#pragma unroll
    for (int q = 0; q < 4; ++q) {
        const int ch = tid + q * 256;
        const int row = ch >> 4, c16 = ch & 15;
        const float* src = Ew + (size_t)widx[row] * EMB + c16 * 8;
        const float4 v0 = *reinterpret_cast<const float4*>(src);
        const float4 v1 = *reinterpret_cast<const float4*>(src + 4);
        short8v pk;
        pk[0] = f2bf(v0.x); pk[1] = f2bf(v0.y); pk[2] = f2bf(v0.z); pk[3] = f2bf(v0.w);
        pk[4] = f2bf(v1.x); pk[5] = f2bf(v1.y); pk[6] = f2bf(v1.z); pk[7] = f2bf(v1.w);
        *reinterpret_cast<short8v*>(&As[row * 128 + ((c16 ^ (row & 7)) << 3)]) = pk;
    }
#pragma unroll
    for (int q = 0; q < 10; ++q) {
        const int ch = tid + q * 256;
        const int col = ch >> 4, c16 = ch & 15;
        const short* src = reinterpret_cast<const short*>(WbT) + (size_t)(n0 + col) * 128 + c16 * 8;
        const short8v v = *reinterpret_cast<const short8v*>(src);
        *reinterpret_cast<short8v*>(&Bs[col * 128 + ((c16 ^ (col & 7)) << 3)]) = v;
    }
    __syncthreads();

    const int w = tid >> 6, l = tid & 63;
    const int lr = l & 15, lg = l >> 4;
    const int arow = w * 16 + lr;

    f32x4 acc[10];
#pragma unroll
    for (int ni = 0; ni < 10; ++ni) acc[ni] = f32x4{0.f, 0.f, 0.f, 0.f};

    const int lay = flag[0];

    if (lay == 0) {
#pragma unroll
        for (int kk = 0; kk < 4; ++kk) {
            const int c16 = kk * 4 + lg;
            const short8v a = *reinterpret_cast<const short8v*>(
                &As[arow * 128 + ((c16 ^ (arow & 7)) << 3)]);
#pragma unroll
            for (int ni = 0; ni < 10; ++ni) {
                const int col = ni * 16 + lr;
                const short8v bfr = *reinterpret_cast<const short8v*>(
                    &Bs[col * 128 + ((c16 ^ (col & 7)) << 3)]);
                acc[ni] = __builtin_amdgcn_mfma_f32_16x16x32_bf16(a, bfr, acc[ni], 0, 0, 0);
            }
        }
    } else {
#pragma unroll
        for (int kk = 0; kk < 4; ++kk) {
            const int ch16 = kk * 4 + (lg >> 1);
            const int inner = (lg & 1) * 4;
            const int alo_i = arow * 128 + ((ch16 ^ (arow & 7)) << 3) + inner;
            const int ahi_i = arow * 128 + (((ch16 + 2) ^ (arow & 7)) << 3) + inner;
            const short4v alo = *reinterpret_cast<const short4v*>(&As[alo_i]);
            const short4v ahi = *reinterpret_cast<const short4v*>(&As[ahi_i]);
            short8v a;
            a[0] = alo[0]; a[1] = alo[1]; a[2] = alo[2]; a[3] = alo[3];
            a[4] = ahi[0]; a[5] = ahi[1]; a[6] = ahi[2]; a[7] = ahi[3];
#pragma unroll
            for (int ni = 0; ni < 10; ++ni) {
                const int col = ni * 16 + lr;
                const int blo_i = col * 128 + ((ch16 ^ (col & 7)) << 3) + inner;
                const int bhi_i = col * 128 + (((ch16 + 2) ^ (col & 7)) << 3) + inner;
                const short4v blo = *reinterpret_cast<const short4v*>(&Bs[blo_i]);
                const short4v bhi = *reinterpret_cast<const short4v*>(&Bs[bhi_i]);
                short8v b;
                b[0] = blo[0]; b[1] = blo[1]; b[2] = blo[2]; b[3] = blo[3];
                b[4] = bhi[0]; b[5] = bhi[1]; b[6] = bhi[2]; b[7] = bhi[3];
                acc[ni] = __builtin_amdgcn_mfma_f32_16x16x32_bf16(a, b, acc[ni], 0, 0, 0);
            }
        }
    }

    // epilogue: add tables, store bf16 into xwF[dir][t][b>>4][unit][b&15] + gate
    const int rbase = w * 16 + lg * 4;
    int pix[4], dix[4];
#pragma unroll
    for (int i = 0; i < 4; ++i) { pix[i] = pidx[rbase + i]; dix[i] = didx[rbase + i]; }
    short* xf = reinterpret_cast<short*>(xwF);
#pragma unroll
    for (int ni = 0; ni < 10; ++ni) {
        const int c = n0 + ni * 16 + lr;
        const int dirg = c >= GATES;
        const int j = c - dirg * GATES;
        const int gate = j / UNITS, unit = j - gate * UNITS;
#pragma unroll
        for (int i = 0; i < 4; ++i) {
            const int b = b0 + rbase + i;
            const float v = acc[ni][i]
                          + Ppos[(size_t)pix[i] * NCOL + c]
                          + Pdep[(size_t)dix[i] * NCOL + c];
            const size_t off8 = ((size_t)(t * 16 + (b >> 4)) * UPAD + unit) * 16 + (b & 15);
            xf[(size_t)dirg * DIRSH + off8 * 4 + gate] = f2bf(v);
        }
    }
}

// ---------------------------------------------------------------------------
// lstm_mfma v4: v3's 2-chain 4-phase pipeline, with (a) fully-coalesced xw
// fragment loads from xwF, (b) h output as f16 via coalesced LDS-plane copy
// folded into the following phase (gate phase touches LDS only).
// Copy schedule (hazard-checked): ph1 copies B(s-1), ph2 A(s), ph3 B(s),
// ph4 A(s+1); epilogue B(255). Every plane-copy is barrier-separated from
// the next write of that plane.
// ---------------------------------------------------------------------------
#define BAR() do { \
    asm volatile("s_waitcnt lgkmcnt(0)" ::: "memory"); \
    __builtin_amdgcn_sched_barrier(0); \
    __builtin_amdgcn_s_barrier(); \
    __builtin_amdgcn_sched_barrier(0); \
} while (0)

__global__ __launch_bounds__(512, 1) void lstm_mfma(
    const int* __restrict__ words,
    const __hip_bfloat16* __restrict__ xwF,
    const float* __restrict__ Uf, const float* __restrict__ Ub,
    const int* __restrict__ flag,
    _Float16* __restrict__ h_f, _Float16* __restrict__ h_b)
{
    const int bk = blockIdx.x;          // 16 blocks
    const int dirv = bk & 1;
    const int tp = bk >> 1;             // tile-pair 0..7
    const int b0A = tp * 32, b0B = tp * 32 + 16;
    const int tileA = b0A >> 4, tileB = b0B >> 4;
    const float* U = dirv ? Ub : Uf;
    _Float16* hout = dirv ? h_b : h_f;

    __shared__ _Float16 plA[16 * HROW], plB[16 * HROW];
    __shared__ unsigned char mA[T_LEN * 16], mB[T_LEN * 16];

    const int tid = threadIdx.x;
    const int w = tid >> 6, l = tid & 63, lr = l & 15, lg = l >> 4;
    const int lay = flag[1];

    for (int i = tid; i < 16 * HROW; i += 512) { plA[i] = (_Float16)0.f; plB[i] = (_Float16)0.f; }
    for (int i = tid; i < T_LEN * 16; i += 512) {
        const int row = i & 15, tt = i >> 4;
        mA[i] = (unsigned char)(words[(size_t)(b0A + row) * T_LEN + tt] != 0);
        mB[i] = (unsigned char)(words[(size_t)(b0B + row) * T_LEN + tt] != 0);
    }

    // A-frags of U'^T (cols = unit*4+gate), register resident f16.
    half8 uf[NTILE][4];
    bool actT[NTILE];
    int ub[NTILE];
#pragma unroll
    for (int nt = 0; nt < NTILE; ++nt) {
        const int ntg = w * NTILE + nt;
        actT[nt] = (ntg * 4) < UNITS;
        ub[nt] = ntg * 4 + lg;          // this lane's unit (D-side / xwF index)
        const int colA = ntg * 16 + lr; // A-row m: unit = colA/4, gate = colA&3
        const int uA = colA >> 2, gA = colA & 3;
#pragma unroll
        for (int kk = 0; kk < 4; ++kk) {
#pragma unroll
            for (int e = 0; e < 8; ++e) {
                const int kl = lay ? ((e >> 2) * 16 + lg * 4 + (e & 3)) : (lg * 8 + e);
                const int k = kk * 32 + kl;
                const float v = (k < UNITS && uA < UNITS)
                              ? U[(size_t)k * GATES + gA * UNITS + uA] : 0.f;
                uf[nt][kk][e] = (_Float16)v;
            }
        }
    }

    float cqA[NTILE] = {0,0,0,0}, hqA[NTILE] = {0,0,0,0};
    float cqB[NTILE] = {0,0,0,0}, hqB[NTILE] = {0,0,0,0};

    __syncthreads();

    const int t0 = dirv ? (T_LEN - 1) : 0;
    const int dt = dirv ? -1 : 1;
    auto tc = [&](int s) { int t = t0 + dt * s; return t < 0 ? 0 : (t > T_LEN - 1 ? T_LEN - 1 : t); };

    const uint2* xq = reinterpret_cast<const uint2*>(xwF) + (size_t)dirv * DIRSZ8;

    uint2 pfA[NTILE], pfB[NTILE], pfA2[NTILE], pfB2[NTILE];
#pragma unroll
    for (int nt = 0; nt < NTILE; ++nt) {
        if (actT[nt]) {
            pfA[nt] = xq[((size_t)(t0 * 16 + tileA) * UPAD + ub[nt]) * 16 + lr];
            pfB[nt] = xq[((size_t)(t0 * 16 + tileB) * UPAD + ub[nt]) * 16 + lr];
        }
    }

    f32x4 accA[NTILE], accB[NTILE];

    auto mfma_ph = [&](const _Float16* pl, f32x4 (&acc)[NTILE], uint2 (&pfc)[NTILE],
                       uint2 (&pfn)[NTILE], int tile, int tn) {
#pragma unroll
        for (int nt = 0; nt < NTILE; ++nt)
            if (actT[nt])
                pfn[nt] = xq[((size_t)(tn * 16 + tile) * UPAD + ub[nt]) * 16 + lr];
        half8 af[4];
        if (lay == 0) {
#pragma unroll
            for (int kk = 0; kk < 4; ++kk)
                af[kk] = *reinterpret_cast<const half8*>(&pl[lr * HROW + kk * 32 + lg * 8]);
        } else {
#pragma unroll
            for (int kk = 0; kk < 4; ++kk) {
                const half4 x0 = *reinterpret_cast<const half4*>(&pl[lr * HROW + kk * 32 + lg * 4]);
                const half4 x1 = *reinterpret_cast<const half4*>(&pl[lr * HROW + kk * 32 + 16 + lg * 4]);
                half8 tv;
                tv[0] = x0[0]; tv[1] = x0[1]; tv[2] = x0[2]; tv[3] = x0[3];
                tv[4] = x1[0]; tv[5] = x1[1]; tv[6] = x1[2]; tv[7] = x1[3];
                af[kk] = tv;
            }
        }
#pragma unroll
        for (int nt = 0; nt < NTILE; ++nt) {
            if (!actT[nt]) continue;
            f32x4 a = {0.f, 0.f, 0.f, 0.f};
#pragma unroll
            for (int kk = 0; kk < 4; ++kk)
                a = __builtin_amdgcn_mfma_f32_16x16x32_f16(uf[nt][kk], af[kk], a, 0, 0, 0);
            a[0] += bf2f((short)(pfc[nt].x & 0xffff));
            a[1] += bf2f((short)(pfc[nt].x >> 16));
            a[2] += bf2f((short)(pfc[nt].y & 0xffff));
            a[3] += bf2f((short)(pfc[nt].y >> 16));
            acc[nt] = a;
        }
    };

    auto gate_ph = [&](f32x4 (&acc)[NTILE], float (&cq)[NTILE], float (&hq)[NTILE],
                       _Float16* pl, const unsigned char* msk, int t) {
        const bool m = msk[t * 16 + lr] != 0;
#pragma unroll
        for (int nt = 0; nt < NTILE; ++nt) {
            if (!actT[nt]) continue;
            const float ig = fast_sigmoid(acc[nt][0]);
            const float fg = fast_sigmoid(acc[nt][1]);
            const float gg = fast_tanh(acc[nt][2]);
            const float og = fast_sigmoid(acc[nt][3]);
            const float cn = fg * cq[nt] + ig * gg;
            const float hn = og * fast_tanh(cn);
            const float h2 = m ? hn : hq[nt];
            cq[nt] = m ? cn : cq[nt];
            hq[nt] = h2;
            pl[lr * HROW + ub[nt]] = (_Float16)h2;   // LDS only
        }
    };

    // coalesced plane -> global f16 copy: thread i writes dword i of the
    // 16x100-f16 block at hout[(t*256+bc)*100]
    auto copy_ph = [&](const _Float16* pl, int bc, int t) {
        unsigned* dst = reinterpret_cast<unsigned*>(hout + ((size_t)t * B_SZ + bc) * UNITS);
        const unsigned* src = reinterpret_cast<const unsigned*>(pl);
        for (int i = tid; i < 800; i += 512) {
            const int row = i / 50, pr = i - row * 50;
            dst[i] = src[row * (HROW / 2) + pr];
        }
    };

    // prologue
    mfma_ph(plA, accA, pfA, pfA2, tileA, tc(1));
    BAR();

    for (int s = 0; s < T_LEN; s += 2) {
        const int ta = tc(s), tb = tc(s + 1);
        // ph1: MFMA_B(s) || gates_A(s) || copy_B(s-1)
        mfma_ph(plB, accB, pfB, pfB2, tileB, tc(s + 1));
        gate_ph(accA, cqA, hqA, plA, mA, ta);
        if (s) copy_ph(plB, b0B, tc(s - 1));
        BAR();
        // ph2: MFMA_A(s+1) || gates_B(s) || copy_A(s)
        mfma_ph(plA, accA, pfA2, pfA, tileA, tc(s + 2));
        gate_ph(accB, cqB, hqB, plB, mB, ta);
        copy_ph(plA, b0A, ta);
        BAR();
        // ph3: MFMA_B(s+1) || gates_A(s+1) || copy_B(s)
        mfma_ph(plB, accB, pfB2, pfB, tileB, tc(s + 2));
        gate_ph(accA, cqA, hqA, plA, mA, tb);
        copy_ph(plB, b0B, ta);
        BAR();
        // ph4: MFMA_A(s+2) || gates_B(s+1) || copy_A(s+1)
        if (s + 2 < T_LEN)
            mfma_ph(plA, accA, pfA, pfA2, tileA, tc(s + 3));
        gate_ph(accB, cqB, hqB, plB, mB, tb);
        copy_ph(plA, b0A, tb);
        BAR();
    }
    // epilogue: copy_B(255)
    copy_ph(plB, b0B, tc(T_LEN - 1));
}

// ---------------------------------------------------------------------------
// out_proj: out[b][t] = sigmoid(h_f . Wo[0:100] + h_b . Wo[100:200] + bo)
// h now f16.
// ---------------------------------------------------------------------------
__global__ __launch_bounds__(256) void out_proj(
    const _Float16* __restrict__ h_f, const _Float16* __restrict__ h_b,
    const float* __restrict__ Wo, const float* __restrict__ bo,
    float* __restrict__ out)
{
    const int tid = threadIdx.x;
    const int g = tid >> 2, sub = tid & 3;
    const int r = blockIdx.x * 64 + g;      // r = t*256 + b
    const int t = r >> 8, b = r & 255;

    const _Float16* hf = h_f + (size_t)r * UNITS;
    const _Float16* hb = h_b + (size_t)r * UNITS;

    float s = 0.f;
    const int k0 = sub * 25;
#pragma unroll
    for (int k = 0; k < 25; ++k) s = fmaf((float)hf[k0 + k], Wo[k0 + k], s);
#pragma unroll
    for (int k = 0; k < 25; ++k) s = fmaf((float)hb[k0 + k], Wo[UNITS + k0 + k], s);

    s += __shfl_xor(s, 1);
    s += __shfl_xor(s, 2);

    if (sub == 0)
        out[(size_t)b * T_LEN + t] = 1.f / (1.f + __expf(-(s + bo[0])));
}

// ---------------------------------------------------------------------------
extern "C" void kernel_launch(void* const* d_in, const int* in_sizes, int n_in,
                              void* d_out, int out_size, void* d_ws, size_t ws_size,
                              hipStream_t stream)
{
    const int*   words = (const int*)d_in[0];
    const int*   pos   = (const int*)d_in[1];
    const int*   dep   = (const int*)d_in[2];
    const float* Ew    = (const float*)d_in[3];
    const float* Ep    = (const float*)d_in[4];
    const float* Ed    = (const float*)d_in[5];
    const float* Wf    = (const float*)d_in[6];
    const float* Uf    = (const float*)d_in[7];
    const float* bf_   = (const float*)d_in[8];
    const float* Wb    = (const float*)d_in[9];
    const float* Ub    = (const float*)d_in[10];
    const float* bb_   = (const float*)d_in[11];
    const float* Wo    = (const float*)d_in[12];
    const float* bo    = (const float*)d_in[13];
    float* out = (float*)d_out;

    auto alignup = [](size_t x) { return (x + 255) & ~(size_t)255; };
    char* p = (char*)d_ws;
    __hip_bfloat16* xwF = (__hip_bfloat16*)p; p += alignup(DIRSH * 2 * sizeof(short));  // 2 dirs
    _Float16* h_f = (_Float16*)p;             p += alignup((size_t)T_LEN * B_SZ * UNITS * 2);
    _Float16* h_b = (_Float16*)p;             p += alignup((size_t)T_LEN * B_SZ * UNITS * 2);
    __hip_bfloat16* WbT = (__hip_bfloat16*)p; p += alignup((size_t)NCOL * 128 * 2);
    float* Ppos = (float*)p;                  p += alignup((size_t)53 * NCOL * 4);
    float* Pdep = (float*)p;                  p += alignup((size_t)54 * NCOL * 4);
    int* flag = (int*)p;

    prep<<<dim3(PREP_WT_BLOCKS + PREP_TAB_BLOCKS + 1), 256, 0, stream>>>(
        Wf, Wb, bf_, bb_, Ep, Ed, WbT, Ppos, Pdep, flag);

    embed_gemm<<<dim3((T_LEN * B_SZ) / MT, NCOL / NT), 256, 0, stream>>>(
        words, pos, dep, Ew, WbT, Ppos, Pdep, flag, xwF);

    lstm_mfma<<<dim3(16), 512, 0, stream>>>(
        words, xwF, Uf, Ub, flag, h_f, h_b);

    out_proj<<<dim3((T_LEN * B_SZ) / 64), 256, 0, stream>>>(h_f, h_b, Wo, bo, out);
}

// Round 10
// 351.748 us; speedup vs baseline: 3.9087x; 3.9087x over previous
//
#include <hip/hip_runtime.h>
#include <hip/hip_bf16.h>

#define T_LEN 256
#define B_SZ  256
#define EMB   128
#define UNITS 100
#define GATES 400           // 4*UNITS
#define NCOL  800           // [fwd 400 | bwd 400], j = gate*100+unit within dir
#define NQ    52            // f16 k-pairs (104 padded k)

typedef __attribute__((ext_vector_type(8))) short short8v;
typedef __attribute__((ext_vector_type(4))) short short4v;
typedef __attribute__((ext_vector_type(4))) float f32x4;
typedef _Float16 half2v __attribute__((ext_vector_type(2)));

static __device__ __forceinline__ float bf2f(short s) {
    unsigned u = ((unsigned)(unsigned short)s) << 16;
    return __builtin_bit_cast(float, u);
}
static __device__ __forceinline__ short f2bf(float f) {
    return __builtin_bit_cast(short, __float2bfloat16(f));
}
static __device__ __forceinline__ float fast_sigmoid(float x) {
    return 1.f / (1.f + __expf(-x));
}
static __device__ __forceinline__ float fast_tanh(float x) {
    return 1.f - 2.f / (1.f + __expf(2.f * x));
}
static __device__ __forceinline__ float fdot2p(unsigned hp, unsigned up, float c) {
#if __has_builtin(__builtin_amdgcn_fdot2)
    return __builtin_amdgcn_fdot2(__builtin_bit_cast(half2v, hp),
                                  __builtin_bit_cast(half2v, up), c, false);
#else
    const half2v a = __builtin_bit_cast(half2v, hp);
    const half2v b = __builtin_bit_cast(half2v, up);
    return fmaf((float)a[1], (float)b[1], fmaf((float)a[0], (float)b[0], c));
#endif
}

// ---------------------------------------------------------------------------
// prep: (a) WbT bf16 transposed word-part weights (c = dir*400+j, k-major 128)
//       (b) P_pos/P_dep tables (dep absorbs bias)
//       (c) Upk[dir][q][col]: f16 pair (U[2q][col], U[2q+1][col]), q<52
//       (d) bf16 MFMA layout probe -> flag[0]
// ---------------------------------------------------------------------------
#define PREP_WT_BLOCKS 100
#define PREP_TAB_BLOCKS 107
#define PREP_UPK_BLOCKS 21

__global__ __launch_bounds__(256) void prep(
    const float* __restrict__ Wf, const float* __restrict__ Wb,
    const float* __restrict__ bf_, const float* __restrict__ bb_,
    const float* __restrict__ Ep, const float* __restrict__ Ed,
    const float* __restrict__ Uf, const float* __restrict__ Ub,
    __hip_bfloat16* __restrict__ WbT, float* __restrict__ Ppos,
    float* __restrict__ Pdep, unsigned* __restrict__ Upk, int* __restrict__ flag)
{
    __shared__ short Ap[16 * 32];
    __shared__ short Bp[32 * 16];

    const int bx = blockIdx.x, tid = threadIdx.x;

    if (bx < PREP_WT_BLOCKS) {
        const int base = bx * 1024 + tid * 4;
#pragma unroll
        for (int q = 0; q < 4; ++q) {
            const int id = base + q;            // id = c*128 + k
            const int c = id >> 7, k = id & 127;
            const int dir = c >= GATES;
            const int j = c - dir * GATES;
            const float* W = dir ? Wb : Wf;
            WbT[id] = __float2bfloat16(W[k * GATES + j]);
        }
    } else if (bx < PREP_WT_BLOCKS + PREP_TAB_BLOCKS) {
        const int p = bx - PREP_WT_BLOCKS;
        const bool isPos = p < 53;
        const float* Erow = isPos ? (Ep + p * EMB) : (Ed + (size_t)(p - 53) * EMB);
        const int rowoff = isPos ? EMB : 2 * EMB;
        float* dst = isPos ? (Ppos + (size_t)p * NCOL) : (Pdep + (size_t)(p - 53) * NCOL);
        for (int c = tid; c < NCOL; c += 256) {
            const int dir = c >= GATES;
            const int j = c - dir * GATES;
            const float* W = dir ? Wb : Wf;
            float s = 0.f;
            for (int k = 0; k < EMB; ++k)
                s = fmaf(Erow[k], W[(size_t)(rowoff + k) * GATES + j], s);
            if (!isPos) s += (dir ? bb_[j] : bf_[j]);
            dst[c] = s;
        }
    } else if (bx < PREP_WT_BLOCKS + PREP_TAB_BLOCKS + PREP_UPK_BLOCKS) {
        const int p2 = bx - PREP_WT_BLOCKS - PREP_TAB_BLOCKS;
#pragma unroll
        for (int i = 0; i < 8; ++i) {
            const int e = p2 * 2048 + tid * 8 + i;     // e = dir*20800 + q*400 + col
            if (e < 2 * NQ * GATES) {
                const int dir = e / (NQ * GATES);
                const int rem = e - dir * (NQ * GATES);
                const int q = rem / GATES, col = rem - q * GATES;
                const float* U = dir ? Ub : Uf;
                const int k0 = 2 * q, k1 = 2 * q + 1;
                const float v0 = (k0 < UNITS) ? U[(size_t)k0 * GATES + col] : 0.f;
                const float v1 = (k1 < UNITS) ? U[(size_t)k1 * GATES + col] : 0.f;
                const unsigned lo = (unsigned)(unsigned short)__builtin_bit_cast(short, (_Float16)v0);
                const unsigned hi = (unsigned)(unsigned short)__builtin_bit_cast(short, (_Float16)v1);
                Upk[e] = lo | (hi << 16);
            }
        }
    } else {
        // ---- bf16 MFMA layout probe ----
        if (tid < 64) {
            for (int e = tid; e < 512; e += 64) {
                const int m = e >> 5, k = e & 31;
                Ap[e] = f2bf((float)((m * 3 + k * 5) % 7 - 3));
            }
            for (int e = tid; e < 512; e += 64) {
                const int k = e >> 4, n = e & 15;
                Bp[e] = f2bf((float)((k * 7 + n * 3) % 5 - 2));
            }
        }
        __syncthreads();
        if (tid < 64) {
            const int l = tid, mn = l & 15, grp = l >> 4;
            float ref[4];
#pragma unroll
            for (int i = 0; i < 4; ++i) {
                const int m = grp * 4 + i;
                float s = 0.f;
                for (int k = 0; k < 32; ++k)
                    s += bf2f(Ap[m * 32 + k]) * bf2f(Bp[k * 16 + mn]);
                ref[i] = s;
            }
            short8v a8, b8;
#pragma unroll
            for (int e = 0; e < 8; ++e) {
                const int k8 = grp * 8 + e;
                a8[e] = Ap[mn * 32 + k8];
                b8[e] = Bp[k8 * 16 + mn];
            }
            f32x4 z = {0.f, 0.f, 0.f, 0.f};
            f32x4 d8 = __builtin_amdgcn_mfma_f32_16x16x32_bf16(a8, b8, z, 0, 0, 0);
            const bool ok8 = (d8[0] == ref[0]) && (d8[1] == ref[1]) &&
                             (d8[2] == ref[2]) && (d8[3] == ref[3]);
            const unsigned long long m8 = __ballot(ok8);
            if (tid == 0) flag[0] = (m8 == ~0ULL) ? 0 : 1;
        }
    }
}

// ---------------------------------------------------------------------------
// embed_gemm: xw[r][c] bf16, r = t*256+b, c = dir*400 + gate*100 + unit
// (round-3 proven structure)
// ---------------------------------------------------------------------------
#define MT 64
#define NT 160

__global__ __launch_bounds__(256) void embed_gemm(
    const int* __restrict__ words, const int* __restrict__ pos, const int* __restrict__ dep,
    const float* __restrict__ Ew, const __hip_bfloat16* __restrict__ WbT,
    const float* __restrict__ Ppos, const float* __restrict__ Pdep,
    const int* __restrict__ flag, __hip_bfloat16* __restrict__ xw)
{
    __shared__ __align__(16) short As[MT * 128];
    __shared__ __align__(16) short Bs[NT * 128];
    __shared__ int widx[MT], pidx[MT], didx[MT];

    const int tid = threadIdx.x;
    const int bx = blockIdx.x, by = blockIdx.y;
    const int r0 = bx * MT;
    const int t = r0 >> 8, b0 = r0 & 255;
    const int n0 = by * NT;

    if (tid < MT)             widx[tid]          = words[(size_t)(b0 + tid) * T_LEN + t];
    else if (tid < 2 * MT)    pidx[tid - MT]     = pos[(size_t)(b0 + tid - MT) * T_LEN + t];
    else if (tid < 3 * MT)    didx[tid - 2 * MT] = dep[(size_t)(b0 + tid - 2 * MT) * T_LEN + t];
    __syncthreads();

#pragma unroll
    for (int q = 0; q < 4; ++q) {
        const int ch = tid + q * 256;
        const int row = ch >> 4, c16 = ch & 15;
        const float* src = Ew + (size_t)widx[row] * EMB + c16 * 8;
        const float4 v0 = *reinterpret_cast<const float4*>(src);
        const float4 v1 = *reinterpret_cast<const float4*>(src + 4);
        short8v pk;
        pk[0] = f2bf(v0.x); pk[1] = f2bf(v0.y); pk[2] = f2bf(v0.z); pk[3] = f2bf(v0.w);
        pk[4] = f2bf(v1.x); pk[5] = f2bf(v1.y); pk[6] = f2bf(v1.z); pk[7] = f2bf(v1.w);
        *reinterpret_cast<short8v*>(&As[row * 128 + ((c16 ^ (row & 7)) << 3)]) = pk;
    }
#pragma unroll
    for (int q = 0; q < 10; ++q) {
        const int ch = tid + q * 256;
        const int col = ch >> 4, c16 = ch & 15;
        const short* src = reinterpret_cast<const short*>(WbT) + (size_t)(n0 + col) * 128 + c16 * 8;
        const short8v v = *reinterpret_cast<const short8v*>(src);
        *reinterpret_cast<short8v*>(&Bs[col * 128 + ((c16 ^ (col & 7)) << 3)]) = v;
    }
    __syncthreads();

    const int w = tid >> 6, l = tid & 63;
    const int lr = l & 15, lg = l >> 4;
    const int arow = w * 16 + lr;

    f32x4 acc[10];
#pragma unroll
    for (int ni = 0; ni < 10; ++ni) acc[ni] = f32x4{0.f, 0.f, 0.f, 0.f};

    const int lay = flag[0];

    if (lay == 0) {
#pragma unroll
        for (int kk = 0; kk < 4; ++kk) {
            const int c16 = kk * 4 + lg;
            const short8v a = *reinterpret_cast<const short8v*>(
                &As[arow * 128 + ((c16 ^ (arow & 7)) << 3)]);
#pragma unroll
            for (int ni = 0; ni < 10; ++ni) {
                const int col = ni * 16 + lr;
                const short8v bfr = *reinterpret_cast<const short8v*>(
                    &Bs[col * 128 + ((c16 ^ (col & 7)) << 3)]);
                acc[ni] = __builtin_amdgcn_mfma_f32_16x16x32_bf16(a, bfr, acc[ni], 0, 0, 0);
            }
        }
    } else {
#pragma unroll
        for (int kk = 0; kk < 4; ++kk) {
            const int ch16 = kk * 4 + (lg >> 1);
            const int inner = (lg & 1) * 4;
            const int alo_i = arow * 128 + ((ch16 ^ (arow & 7)) << 3) + inner;
            const int ahi_i = arow * 128 + (((ch16 + 2) ^ (arow & 7)) << 3) + inner;
            const short4v alo = *reinterpret_cast<const short4v*>(&As[alo_i]);
            const short4v ahi = *reinterpret_cast<const short4v*>(&As[ahi_i]);
            short8v a;
            a[0] = alo[0]; a[1] = alo[1]; a[2] = alo[2]; a[3] = alo[3];
            a[4] = ahi[0]; a[5] = ahi[1]; a[6] = ahi[2]; a[7] = ahi[3];
#pragma unroll
            for (int ni = 0; ni < 10; ++ni) {
                const int col = ni * 16 + lr;
                const int blo_i = col * 128 + ((ch16 ^ (col & 7)) << 3) + inner;
                const int bhi_i = col * 128 + (((ch16 + 2) ^ (col & 7)) << 3) + inner;
                const short4v blo = *reinterpret_cast<const short4v*>(&Bs[blo_i]);
                const short4v bhi = *reinterpret_cast<const short4v*>(&Bs[bhi_i]);
                short8v b;
                b[0] = blo[0]; b[1] = blo[1]; b[2] = blo[2]; b[3] = blo[3];
                b[4] = bhi[0]; b[5] = bhi[1]; b[6] = bhi[2]; b[7] = bhi[3];
                acc[ni] = __builtin_amdgcn_mfma_f32_16x16x32_bf16(a, b, acc[ni], 0, 0, 0);
            }
        }
    }

    const int rbase = w * 16 + lg * 4;
    int pix[4], dix[4];
#pragma unroll
    for (int i = 0; i < 4; ++i) { pix[i] = pidx[rbase + i]; dix[i] = didx[rbase + i]; }
#pragma unroll
    for (int ni = 0; ni < 10; ++ni) {
        const int c = n0 + ni * 16 + lr;
#pragma unroll
        for (int i = 0; i < 4; ++i) {
            const float v = acc[ni][i]
                          + Ppos[(size_t)pix[i] * NCOL + c]
                          + Pdep[(size_t)dix[i] * NCOL + c];
            xw[(size_t)(r0 + rbase + i) * NCOL + c] = __float2bfloat16(v);
        }
    }
}

// ---------------------------------------------------------------------------
// lstm_valu: one block per (b, dir) chain -> 512 blocks, ~2 co-resident/CU.
// Thread j<400 owns gate-column j with U as 52 f16-pair VGPRs (v_dot2_f32_f16,
// f32 accumulate); h broadcast from LDS f16[104] via 13 uniform ds_read_b128.
// Threads <100 run gates (c,h in regs), write h f16 to LDS + global.
// Raw lgkmcnt-only barriers; xw prefetched one step ahead.
// FIX vs r9: zero ALL 52 dwords of h_sh (was 26 -> units 52..99 read
// uninitialized LDS at step 0).
// ---------------------------------------------------------------------------
#define BAR() do { \
    asm volatile("s_waitcnt lgkmcnt(0)" ::: "memory"); \
    __builtin_amdgcn_sched_barrier(0); \
    __builtin_amdgcn_s_barrier(); \
    __builtin_amdgcn_sched_barrier(0); \
} while (0)

__global__ __launch_bounds__(512, 1) void lstm_valu(
    const int* __restrict__ words,
    const __hip_bfloat16* __restrict__ xw,
    const unsigned* __restrict__ Upk,
    _Float16* __restrict__ h_f, _Float16* __restrict__ h_b)
{
    const int b = blockIdx.x >> 1, dirv = blockIdx.x & 1;
    _Float16* hout = dirv ? h_b : h_f;
    const int coff = dirv * GATES;
    const unsigned* up = Upk + (size_t)dirv * NQ * GATES;

    __shared__ __align__(16) _Float16 h_sh[104];
    __shared__ float z_sh[GATES];
    __shared__ unsigned char m_sh[T_LEN];

    const int tid = threadIdx.x;
    const bool isCol = tid < GATES;

    for (int i = tid; i < T_LEN; i += 512)
        m_sh[i] = (unsigned char)(words[(size_t)b * T_LEN + i] != 0);
    if (tid < 52) reinterpret_cast<unsigned*>(h_sh)[tid] = 0u;   // all 104 f16

    unsigned upk[NQ];
    if (isCol) {
#pragma unroll
        for (int q = 0; q < NQ; ++q) upk[q] = up[q * GATES + tid];
    }
    float c = 0.f, h = 0.f;
    __syncthreads();

    const int t0 = dirv ? (T_LEN - 1) : 0;
    const int dt = dirv ? -1 : 1;
    const short* xs = reinterpret_cast<const short*>(xw);

    short pf = 0;
    if (isCol) pf = xs[((size_t)t0 * B_SZ + b) * NCOL + coff + tid];

    for (int s = 0; s < T_LEN; ++s) {
        const int t = t0 + dt * s;
        int tn = t + dt; tn = tn < 0 ? 0 : (tn > T_LEN - 1 ? T_LEN - 1 : tn);

        short pfn = pf;
        if (isCol) {
            const float zx = bf2f(pf);
            pfn = xs[((size_t)tn * B_SZ + b) * NCOL + coff + tid];   // prefetch
            float a0 = 0.f, a1 = 0.f, a2 = 0.f, a3 = 0.f;
            const uint4* h4 = reinterpret_cast<const uint4*>(h_sh);
#pragma unroll
            for (int qq = 0; qq < 13; ++qq) {
                const uint4 hv = h4[qq];
                a0 = fdot2p(hv.x, upk[4 * qq + 0], a0);
                a1 = fdot2p(hv.y, upk[4 * qq + 1], a1);
                a2 = fdot2p(hv.z, upk[4 * qq + 2], a2);
                a3 = fdot2p(hv.w, upk[4 * qq + 3], a3);
            }
            z_sh[tid] = zx + (a0 + a1) + (a2 + a3);
        }
        pf = pfn;

        BAR();

        if (tid < UNITS) {
            const float zi = z_sh[tid];
            const float zf = z_sh[tid + UNITS];
            const float zg = z_sh[tid + 2 * UNITS];
            const float zo = z_sh[tid + 3 * UNITS];
            const float ig = fast_sigmoid(zi);
            const float fg = fast_sigmoid(zf);
            const float gg = fast_tanh(zg);
            const float og = fast_sigmoid(zo);
            const float cn = fg * c + ig * gg;
            const float hn = og * fast_tanh(cn);
            const bool  m  = m_sh[t] != 0;
            h = m ? hn : h;
            c = m ? cn : c;
            const _Float16 hh = (_Float16)h;
            h_sh[tid] = hh;
            hout[((size_t)t * B_SZ + b) * UNITS + tid] = hh;
        }

        BAR();
    }
}

// ---------------------------------------------------------------------------
// out_proj: out[b][t] = sigmoid(h_f . Wo[0:100] + h_b . Wo[100:200] + bo)
// ---------------------------------------------------------------------------
__global__ __launch_bounds__(256) void out_proj(
    const _Float16* __restrict__ h_f, const _Float16* __restrict__ h_b,
    const float* __restrict__ Wo, const float* __restrict__ bo,
    float* __restrict__ out)
{
    const int tid = threadIdx.x;
    const int g = tid >> 2, sub = tid & 3;
    const int r = blockIdx.x * 64 + g;      // r = t*256 + b
    const int t = r >> 8, b = r & 255;

    const _Float16* hf = h_f + (size_t)r * UNITS;
    const _Float16* hb = h_b + (size_t)r * UNITS;

    float s = 0.f;
    const int k0 = sub * 25;
#pragma unroll
    for (int k = 0; k < 25; ++k) s = fmaf((float)hf[k0 + k], Wo[k0 + k], s);
#pragma unroll
    for (int k = 0; k < 25; ++k) s = fmaf((float)hb[k0 + k], Wo[UNITS + k0 + k], s);

    s += __shfl_xor(s, 1);
    s += __shfl_xor(s, 2);

    if (sub == 0)
        out[(size_t)b * T_LEN + t] = 1.f / (1.f + __expf(-(s + bo[0])));
}

// ---------------------------------------------------------------------------
extern "C" void kernel_launch(void* const* d_in, const int* in_sizes, int n_in,
                              void* d_out, int out_size, void* d_ws, size_t ws_size,
                              hipStream_t stream)
{
    const int*   words = (const int*)d_in[0];
    const int*   pos   = (const int*)d_in[1];
    const int*   dep   = (const int*)d_in[2];
    const float* Ew    = (const float*)d_in[3];
    const float* Ep    = (const float*)d_in[4];
    const float* Ed    = (const float*)d_in[5];
    const float* Wf    = (const float*)d_in[6];
    const float* Uf    = (const float*)d_in[7];
    const float* bf_   = (const float*)d_in[8];
    const float* Wb    = (const float*)d_in[9];
    const float* Ub    = (const float*)d_in[10];
    const float* bb_   = (const float*)d_in[11];
    const float* Wo    = (const float*)d_in[12];
    const float* bo    = (const float*)d_in[13];
    float* out = (float*)d_out;

    auto alignup = [](size_t x) { return (x + 255) & ~(size_t)255; };
    char* p = (char*)d_ws;
    __hip_bfloat16* xw = (__hip_bfloat16*)p;  p += alignup((size_t)T_LEN * B_SZ * NCOL * 2);
    _Float16* h_f = (_Float16*)p;             p += alignup((size_t)T_LEN * B_SZ * UNITS * 2);
    _Float16* h_b = (_Float16*)p;             p += alignup((size_t)T_LEN * B_SZ * UNITS * 2);
    __hip_bfloat16* WbT = (__hip_bfloat16*)p; p += alignup((size_t)NCOL * 128 * 2);
    float* Ppos = (float*)p;                  p += alignup((size_t)53 * NCOL * 4);
    float* Pdep = (float*)p;                  p += alignup((size_t)54 * NCOL * 4);
    unsigned* Upk = (unsigned*)p;             p += alignup((size_t)2 * NQ * GATES * 4);
    int* flag = (int*)p;

    prep<<<dim3(PREP_WT_BLOCKS + PREP_TAB_BLOCKS + PREP_UPK_BLOCKS + 1), 256, 0, stream>>>(
        Wf, Wb, bf_, bb_, Ep, Ed, Uf, Ub, WbT, Ppos, Pdep, Upk, flag);

    embed_gemm<<<dim3((T_LEN * B_SZ) / MT, NCOL / NT), 256, 0, stream>>>(
        words, pos, dep, Ew, WbT, Ppos, Pdep, flag, xw);

    lstm_valu<<<dim3(B_SZ * 2), 512, 0, stream>>>(words, xw, Upk, h_f, h_b);

    out_proj<<<dim3((T_LEN * B_SZ) / 64), 256, 0, stream>>>(h_f, h_b, Wo, bo, out);
}

// Round 11
// 350.522 us; speedup vs baseline: 3.9224x; 1.0035x over previous
//
#include <hip/hip_runtime.h>
#include <hip/hip_bf16.h>

#define T_LEN 256
#define B_SZ  256
#define EMB   128
#define UNITS 100
#define GATES 400           // 4*UNITS
#define NCOL  800           // [fwd 400 | bwd 400], j = gate*100+unit within dir
#define NQ    52            // f16 k-pairs (104 padded k)

typedef __attribute__((ext_vector_type(8))) short short8v;
typedef __attribute__((ext_vector_type(4))) short short4v;
typedef __attribute__((ext_vector_type(4))) float f32x4;
typedef _Float16 half2v __attribute__((ext_vector_type(2)));

static __device__ __forceinline__ float bf2f(short s) {
    unsigned u = ((unsigned)(unsigned short)s) << 16;
    return __builtin_bit_cast(float, u);
}
static __device__ __forceinline__ short f2bf(float f) {
    return __builtin_bit_cast(short, __float2bfloat16(f));
}
static __device__ __forceinline__ float fast_sigmoid(float x) {
    return 1.f / (1.f + __expf(-x));
}
static __device__ __forceinline__ float fast_tanh(float x) {
    return 1.f - 2.f / (1.f + __expf(2.f * x));
}
static __device__ __forceinline__ float fdot2p(unsigned hp, unsigned up, float c) {
#if __has_builtin(__builtin_amdgcn_fdot2)
    return __builtin_amdgcn_fdot2(__builtin_bit_cast(half2v, hp),
                                  __builtin_bit_cast(half2v, up), c, false);
#else
    const half2v a = __builtin_bit_cast(half2v, hp);
    const half2v b = __builtin_bit_cast(half2v, up);
    return fmaf((float)a[1], (float)b[1], fmaf((float)a[0], (float)b[0], c));
#endif
}

// ---------------------------------------------------------------------------
// prep: (a) WbT bf16 transposed word-part weights (c = dir*400+j, k-major 128)
//       (b) P_pos/P_dep tables (dep absorbs bias)
//       (c) Upk[dir][q][col]: f16 pair (U[2q][col], U[2q+1][col]), q<52
//       (d) bf16 MFMA layout probe -> flag[0]
// ---------------------------------------------------------------------------
#define PREP_WT_BLOCKS 100
#define PREP_TAB_BLOCKS 107
#define PREP_UPK_BLOCKS 21

__global__ __launch_bounds__(256) void prep(
    const float* __restrict__ Wf, const float* __restrict__ Wb,
    const float* __restrict__ bf_, const float* __restrict__ bb_,
    const float* __restrict__ Ep, const float* __restrict__ Ed,
    const float* __restrict__ Uf, const float* __restrict__ Ub,
    __hip_bfloat16* __restrict__ WbT, float* __restrict__ Ppos,
    float* __restrict__ Pdep, unsigned* __restrict__ Upk, int* __restrict__ flag)
{
    __shared__ short Ap[16 * 32];
    __shared__ short Bp[32 * 16];

    const int bx = blockIdx.x, tid = threadIdx.x;

    if (bx < PREP_WT_BLOCKS) {
        const int base = bx * 1024 + tid * 4;
#pragma unroll
        for (int q = 0; q < 4; ++q) {
            const int id = base + q;            // id = c*128 + k
            const int c = id >> 7, k = id & 127;
            const int dir = c >= GATES;
            const int j = c - dir * GATES;
            const float* W = dir ? Wb : Wf;
            WbT[id] = __float2bfloat16(W[k * GATES + j]);
        }
    } else if (bx < PREP_WT_BLOCKS + PREP_TAB_BLOCKS) {
        const int p = bx - PREP_WT_BLOCKS;
        const bool isPos = p < 53;
        const float* Erow = isPos ? (Ep + p * EMB) : (Ed + (size_t)(p - 53) * EMB);
        const int rowoff = isPos ? EMB : 2 * EMB;
        float* dst = isPos ? (Ppos + (size_t)p * NCOL) : (Pdep + (size_t)(p - 53) * NCOL);
        for (int c = tid; c < NCOL; c += 256) {
            const int dir = c >= GATES;
            const int j = c - dir * GATES;
            const float* W = dir ? Wb : Wf;
            float s = 0.f;
            for (int k = 0; k < EMB; ++k)
                s = fmaf(Erow[k], W[(size_t)(rowoff + k) * GATES + j], s);
            if (!isPos) s += (dir ? bb_[j] : bf_[j]);
            dst[c] = s;
        }
    } else if (bx < PREP_WT_BLOCKS + PREP_TAB_BLOCKS + PREP_UPK_BLOCKS) {
        const int p2 = bx - PREP_WT_BLOCKS - PREP_TAB_BLOCKS;
#pragma unroll
        for (int i = 0; i < 8; ++i) {
            const int e = p2 * 2048 + tid * 8 + i;     // e = dir*20800 + q*400 + col
            if (e < 2 * NQ * GATES) {
                const int dir = e / (NQ * GATES);
                const int rem = e - dir * (NQ * GATES);
                const int q = rem / GATES, col = rem - q * GATES;
                const float* U = dir ? Ub : Uf;
                const int k0 = 2 * q, k1 = 2 * q + 1;
                const float v0 = (k0 < UNITS) ? U[(size_t)k0 * GATES + col] : 0.f;
                const float v1 = (k1 < UNITS) ? U[(size_t)k1 * GATES + col] : 0.f;
                const unsigned lo = (unsigned)(unsigned short)__builtin_bit_cast(short, (_Float16)v0);
                const unsigned hi = (unsigned)(unsigned short)__builtin_bit_cast(short, (_Float16)v1);
                Upk[e] = lo | (hi << 16);
            }
        }
    } else {
        // ---- bf16 MFMA layout probe ----
        if (tid < 64) {
            for (int e = tid; e < 512; e += 64) {
                const int m = e >> 5, k = e & 31;
                Ap[e] = f2bf((float)((m * 3 + k * 5) % 7 - 3));
            }
            for (int e = tid; e < 512; e += 64) {
                const int k = e >> 4, n = e & 15;
                Bp[e] = f2bf((float)((k * 7 + n * 3) % 5 - 2));
            }
        }
        __syncthreads();
        if (tid < 64) {
            const int l = tid, mn = l & 15, grp = l >> 4;
            float ref[4];
#pragma unroll
            for (int i = 0; i < 4; ++i) {
                const int m = grp * 4 + i;
                float s = 0.f;
                for (int k = 0; k < 32; ++k)
                    s += bf2f(Ap[m * 32 + k]) * bf2f(Bp[k * 16 + mn]);
                ref[i] = s;
            }
            short8v a8, b8;
#pragma unroll
            for (int e = 0; e < 8; ++e) {
                const int k8 = grp * 8 + e;
                a8[e] = Ap[mn * 32 + k8];
                b8[e] = Bp[k8 * 16 + mn];
            }
            f32x4 z = {0.f, 0.f, 0.f, 0.f};
            f32x4 d8 = __builtin_amdgcn_mfma_f32_16x16x32_bf16(a8, b8, z, 0, 0, 0);
            const bool ok8 = (d8[0] == ref[0]) && (d8[1] == ref[1]) &&
                             (d8[2] == ref[2]) && (d8[3] == ref[3]);
            const unsigned long long m8 = __ballot(ok8);
            if (tid == 0) flag[0] = (m8 == ~0ULL) ? 0 : 1;
        }
    }
}

// ---------------------------------------------------------------------------
// embed_gemm: xw[r][c] bf16, r = t*256+b, c = dir*400 + gate*100 + unit
// ---------------------------------------------------------------------------
#define MT 64
#define NT 160

__global__ __launch_bounds__(256) void embed_gemm(
    const int* __restrict__ words, const int* __restrict__ pos, const int* __restrict__ dep,
    const float* __restrict__ Ew, const __hip_bfloat16* __restrict__ WbT,
    const float* __restrict__ Ppos, const float* __restrict__ Pdep,
    const int* __restrict__ flag, __hip_bfloat16* __restrict__ xw)
{
    __shared__ __align__(16) short As[MT * 128];
    __shared__ __align__(16) short Bs[NT * 128];
    __shared__ int widx[MT], pidx[MT], didx[MT];

    const int tid = threadIdx.x;
    const int bx = blockIdx.x, by = blockIdx.y;
    const int r0 = bx * MT;
    const int t = r0 >> 8, b0 = r0 & 255;
    const int n0 = by * NT;

    if (tid < MT)             widx[tid]          = words[(size_t)(b0 + tid) * T_LEN + t];
    else if (tid < 2 * MT)    pidx[tid - MT]     = pos[(size_t)(b0 + tid - MT) * T_LEN + t];
    else if (tid < 3 * MT)    didx[tid - 2 * MT] = dep[(size_t)(b0 + tid - 2 * MT) * T_LEN + t];
    __syncthreads();

#pragma unroll
    for (int q = 0; q < 4; ++q) {
        const int ch = tid + q * 256;
        const int row = ch >> 4, c16 = ch & 15;
        const float* src = Ew + (size_t)widx[row] * EMB + c16 * 8;
        const float4 v0 = *reinterpret_cast<const float4*>(src);
        const float4 v1 = *reinterpret_cast<const float4*>(src + 4);
        short8v pk;
        pk[0] = f2bf(v0.x); pk[1] = f2bf(v0.y); pk[2] = f2bf(v0.z); pk[3] = f2bf(v0.w);
        pk[4] = f2bf(v1.x); pk[5] = f2bf(v1.y); pk[6] = f2bf(v1.z); pk[7] = f2bf(v1.w);
        *reinterpret_cast<short8v*>(&As[row * 128 + ((c16 ^ (row & 7)) << 3)]) = pk;
    }
#pragma unroll
    for (int q = 0; q < 10; ++q) {
        const int ch = tid + q * 256;
        const int col = ch >> 4, c16 = ch & 15;
        const short* src = reinterpret_cast<const short*>(WbT) + (size_t)(n0 + col) * 128 + c16 * 8;
        const short8v v = *reinterpret_cast<const short8v*>(src);
        *reinterpret_cast<short8v*>(&Bs[col * 128 + ((c16 ^ (col & 7)) << 3)]) = v;
    }
    __syncthreads();

    const int w = tid >> 6, l = tid & 63;
    const int lr = l & 15, lg = l >> 4;
    const int arow = w * 16 + lr;

    f32x4 acc[10];
#pragma unroll
    for (int ni = 0; ni < 10; ++ni) acc[ni] = f32x4{0.f, 0.f, 0.f, 0.f};

    const int lay = flag[0];

    if (lay == 0) {
#pragma unroll
        for (int kk = 0; kk < 4; ++kk) {
            const int c16 = kk * 4 + lg;
            const short8v a = *reinterpret_cast<const short8v*>(
                &As[arow * 128 + ((c16 ^ (arow & 7)) << 3)]);
#pragma unroll
            for (int ni = 0; ni < 10; ++ni) {
                const int col = ni * 16 + lr;
                const short8v bfr = *reinterpret_cast<const short8v*>(
                    &Bs[col * 128 + ((c16 ^ (col & 7)) << 3)]);
                acc[ni] = __builtin_amdgcn_mfma_f32_16x16x32_bf16(a, bfr, acc[ni], 0, 0, 0);
            }
        }
    } else {
#pragma unroll
        for (int kk = 0; kk < 4; ++kk) {
            const int ch16 = kk * 4 + (lg >> 1);
            const int inner = (lg & 1) * 4;
            const int alo_i = arow * 128 + ((ch16 ^ (arow & 7)) << 3) + inner;
            const int ahi_i = arow * 128 + (((ch16 + 2) ^ (arow & 7)) << 3) + inner;
            const short4v alo = *reinterpret_cast<const short4v*>(&As[alo_i]);
            const short4v ahi = *reinterpret_cast<const short4v*>(&As[ahi_i]);
            short8v a;
            a[0] = alo[0]; a[1] = alo[1]; a[2] = alo[2]; a[3] = alo[3];
            a[4] = ahi[0]; a[5] = ahi[1]; a[6] = ahi[2]; a[7] = ahi[3];
#pragma unroll
            for (int ni = 0; ni < 10; ++ni) {
                const int col = ni * 16 + lr;
                const int blo_i = col * 128 + ((ch16 ^ (col & 7)) << 3) + inner;
                const int bhi_i = col * 128 + (((ch16 + 2) ^ (col & 7)) << 3) + inner;
                const short4v blo = *reinterpret_cast<const short4v*>(&Bs[blo_i]);
                const short4v bhi = *reinterpret_cast<const short4v*>(&Bs[bhi_i]);
                short8v b;
                b[0] = blo[0]; b[1] = blo[1]; b[2] = blo[2]; b[3] = blo[3];
                b[4] = bhi[0]; b[5] = bhi[1]; b[6] = bhi[2]; b[7] = bhi[3];
                acc[ni] = __builtin_amdgcn_mfma_f32_16x16x32_bf16(a, b, acc[ni], 0, 0, 0);
            }
        }
    }

    const int rbase = w * 16 + lg * 4;
    int pix[4], dix[4];
#pragma unroll
    for (int i = 0; i < 4; ++i) { pix[i] = pidx[rbase + i]; dix[i] = didx[rbase + i]; }
#pragma unroll
    for (int ni = 0; ni < 10; ++ni) {
        const int c = n0 + ni * 16 + lr;
#pragma unroll
        for (int i = 0; i < 4; ++i) {
            const float v = acc[ni][i]
                          + Ppos[(size_t)pix[i] * NCOL + c]
                          + Pdep[(size_t)dix[i] * NCOL + c];
            xw[(size_t)(r0 + rbase + i) * NCOL + c] = __float2bfloat16(v);
        }
    }
}

// ---------------------------------------------------------------------------
// lstm_valu: one block per (b, dir) chain -> 512 blocks, ~2 co-resident/CU.
// Thread j<400 owns gate-column j with U as 52 f16-pair VGPRs; h broadcast
// from LDS f16[104] via 13 uniform ds_read_b128; gates by threads <100.
// NEW vs r10: asm "+v" pin on upk[] — the asm may have modified the values,
// so the compiler cannot rematerialize the loads inside the loop (r10 counter
// evidence: VGPR_Count=40 -> U reloaded from L2 every step, ~50% stall).
// ---------------------------------------------------------------------------
#define BAR() do { \
    asm volatile("s_waitcnt lgkmcnt(0)" ::: "memory"); \
    __builtin_amdgcn_sched_barrier(0); \
    __builtin_amdgcn_s_barrier(); \
    __builtin_amdgcn_sched_barrier(0); \
} while (0)

__global__ __launch_bounds__(512, 1) void lstm_valu(
    const int* __restrict__ words,
    const __hip_bfloat16* __restrict__ xw,
    const unsigned* __restrict__ Upk,
    _Float16* __restrict__ h_f, _Float16* __restrict__ h_b)
{
    const int b = blockIdx.x >> 1, dirv = blockIdx.x & 1;
    _Float16* hout = dirv ? h_b : h_f;
    const int coff = dirv * GATES;
    const unsigned* up = Upk + (size_t)dirv * NQ * GATES;

    __shared__ __align__(16) _Float16 h_sh[104];
    __shared__ float z_sh[GATES];
    __shared__ unsigned char m_sh[T_LEN];

    const int tid = threadIdx.x;
    const bool isCol = tid < GATES;
    const int colid = isCol ? tid : (GATES - 1);

    for (int i = tid; i < T_LEN; i += 512)
        m_sh[i] = (unsigned char)(words[(size_t)b * T_LEN + i] != 0);
    if (tid < 52) reinterpret_cast<unsigned*>(h_sh)[tid] = 0u;   // all 104 f16

    unsigned upk[NQ];
#pragma unroll
    for (int q = 0; q < NQ; ++q) upk[q] = up[q * GATES + colid];
    // Pin to VGPRs: "+v" means the asm may alter the value, so reloading from
    // memory is no longer a legal rematerialization.
#pragma unroll
    for (int q = 0; q < NQ; ++q) asm volatile("" : "+v"(upk[q]));

    float c = 0.f, h = 0.f;
    __syncthreads();

    const int t0 = dirv ? (T_LEN - 1) : 0;
    const int dt = dirv ? -1 : 1;
    const short* xs = reinterpret_cast<const short*>(xw);

    short pf = 0;
    if (isCol) pf = xs[((size_t)t0 * B_SZ + b) * NCOL + coff + tid];

    for (int s = 0; s < T_LEN; ++s) {
        const int t = t0 + dt * s;
        int tn = t + dt; tn = tn < 0 ? 0 : (tn > T_LEN - 1 ? T_LEN - 1 : tn);

        short pfn = pf;
        if (isCol) {
            const float zx = bf2f(pf);
            pfn = xs[((size_t)tn * B_SZ + b) * NCOL + coff + tid];   // prefetch
            float a0 = 0.f, a1 = 0.f, a2 = 0.f, a3 = 0.f;
            const uint4* h4 = reinterpret_cast<const uint4*>(h_sh);
#pragma unroll
            for (int qq = 0; qq < 13; ++qq) {
                const uint4 hv = h4[qq];
                a0 = fdot2p(hv.x, upk[4 * qq + 0], a0);
                a1 = fdot2p(hv.y, upk[4 * qq + 1], a1);
                a2 = fdot2p(hv.z, upk[4 * qq + 2], a2);
                a3 = fdot2p(hv.w, upk[4 * qq + 3], a3);
            }
            z_sh[tid] = zx + (a0 + a1) + (a2 + a3);
        }
        pf = pfn;

        BAR();

        if (tid < UNITS) {
            const float zi = z_sh[tid];
            const float zf = z_sh[tid + UNITS];
            const float zg = z_sh[tid + 2 * UNITS];
            const float zo = z_sh[tid + 3 * UNITS];
            const float ig = fast_sigmoid(zi);
            const float fg = fast_sigmoid(zf);
            const float gg = fast_tanh(zg);
            const float og = fast_sigmoid(zo);
            const float cn = fg * c + ig * gg;
            const float hn = og * fast_tanh(cn);
            const bool  m  = m_sh[t] != 0;
            h = m ? hn : h;
            c = m ? cn : c;
            const _Float16 hh = (_Float16)h;
            h_sh[tid] = hh;
            hout[((size_t)t * B_SZ + b) * UNITS + tid] = hh;
        }

        BAR();
    }
}

// ---------------------------------------------------------------------------
// out_proj: out[b][t] = sigmoid(h_f . Wo[0:100] + h_b . Wo[100:200] + bo)
// ---------------------------------------------------------------------------
__global__ __launch_bounds__(256) void out_proj(
    const _Float16* __restrict__ h_f, const _Float16* __restrict__ h_b,
    const float* __restrict__ Wo, const float* __restrict__ bo,
    float* __restrict__ out)
{
    const int tid = threadIdx.x;
    const int g = tid >> 2, sub = tid & 3;
    const int r = blockIdx.x * 64 + g;      // r = t*256 + b
    const int t = r >> 8, b = r & 255;

    const _Float16* hf = h_f + (size_t)r * UNITS;
    const _Float16* hb = h_b + (size_t)r * UNITS;

    float s = 0.f;
    const int k0 = sub * 25;
#pragma unroll
    for (int k = 0; k < 25; ++k) s = fmaf((float)hf[k0 + k], Wo[k0 + k], s);
#pragma unroll
    for (int k = 0; k < 25; ++k) s = fmaf((float)hb[k0 + k], Wo[UNITS + k0 + k], s);

    s += __shfl_xor(s, 1);
    s += __shfl_xor(s, 2);

    if (sub == 0)
        out[(size_t)b * T_LEN + t] = 1.f / (1.f + __expf(-(s + bo[0])));
}

// ---------------------------------------------------------------------------
extern "C" void kernel_launch(void* const* d_in, const int* in_sizes, int n_in,
                              void* d_out, int out_size, void* d_ws, size_t ws_size,
                              hipStream_t stream)
{
    const int*   words = (const int*)d_in[0];
    const int*   pos   = (const int*)d_in[1];
    const int*   dep   = (const int*)d_in[2];
    const float* Ew    = (const float*)d_in[3];
    const float* Ep    = (const float*)d_in[4];
    const float* Ed    = (const float*)d_in[5];
    const float* Wf    = (const float*)d_in[6];
    const float* Uf    = (const float*)d_in[7];
    const float* bf_   = (const float*)d_in[8];
    const float* Wb    = (const float*)d_in[9];
    const float* Ub    = (const float*)d_in[10];
    const float* bb_   = (const float*)d_in[11];
    const float* Wo    = (const float*)d_in[12];
    const float* bo    = (const float*)d_in[13];
    float* out = (float*)d_out;

    auto alignup = [](size_t x) { return (x + 255) & ~(size_t)255; };
    char* p = (char*)d_ws;
    __hip_bfloat16* xw = (__hip_bfloat16*)p;  p += alignup((size_t)T_LEN * B_SZ * NCOL * 2);
    _Float16* h_f = (_Float16*)p;             p += alignup((size_t)T_LEN * B_SZ * UNITS * 2);
    _Float16* h_b = (_Float16*)p;             p += alignup((size_t)T_LEN * B_SZ * UNITS * 2);
    __hip_bfloat16* WbT = (__hip_bfloat16*)p; p += alignup((size_t)NCOL * 128 * 2);
    float* Ppos = (float*)p;                  p += alignup((size_t)53 * NCOL * 4);
    float* Pdep = (float*)p;                  p += alignup((size_t)54 * NCOL * 4);
    unsigned* Upk = (unsigned*)p;             p += alignup((size_t)2 * NQ * GATES * 4);
    int* flag = (int*)p;

    prep<<<dim3(PREP_WT_BLOCKS + PREP_TAB_BLOCKS + PREP_UPK_BLOCKS + 1), 256, 0, stream>>>(
        Wf, Wb, bf_, bb_, Ep, Ed, Uf, Ub, WbT, Ppos, Pdep, Upk, flag);

    embed_gemm<<<dim3((T_LEN * B_SZ) / MT, NCOL / NT), 256, 0, stream>>>(
        words, pos, dep, Ew, WbT, Ppos, Pdep, flag, xw);

    lstm_valu<<<dim3(B_SZ * 2), 512, 0, stream>>>(words, xw, Upk, h_f, h_b);

    out_proj<<<dim3((T_LEN * B_SZ) / 64), 256, 0, stream>>>(h_f, h_b, Wo, bo, out);
}